// Round 12
// baseline (304.816 us; speedup 1.0000x reference)
//
#include <hip/hip_runtime.h>

// SlotAttention on MI355X (gfx950).
// R11: fused f32->bf16 A-staging in the GEMM (deletes the 201 MB d-convert
// pass). A is reg-staged (T14): tile-top global_load_dwordx4 of raw f32,
// tile-end in-reg cvt + ds_write_b128 into the SAME swizzled bf16 LDS layout
// as R10 (read path, B-path, 4-slot ring, boundaries unchanged).
// cvt pass shrinks to weights-only (12 MB). attn/reduce unchanged.
// GEMM structure = R2/R10 (best of 8 measured schedules).

#define TS 64
#define TD 4096
#define BATCH 8
#define HC 1024
#define NHEAD 16
#define MD (TD*BATCH)   // 32768
#define MS (TS*BATCH)   // 512
#define NCHUNK 8
#define CHTOK (TD/NCHUNK) // 512

#define KTILES 32       // K=1024 / BK=32

typedef __attribute__((ext_vector_type(8))) __bf16 bf16x8;
typedef __attribute__((ext_vector_type(4))) float f32x4;
typedef __attribute__((ext_vector_type(4))) unsigned short u16x4;
typedef __attribute__((ext_vector_type(8))) unsigned short u16x8;

__device__ __forceinline__ unsigned short f2bf(float x){
  union { float f; unsigned u; } v; v.f = x;
  unsigned r = v.u + 0x7FFFu + ((v.u >> 16) & 1u);
  return (unsigned short)(r >> 16);
}

__device__ __forceinline__ void gll16(const void* g, void* l){
  __builtin_amdgcn_global_load_lds((__attribute__((address_space(1))) void*)g,
                                   (__attribute__((address_space(3))) void*)l, 16, 0, 0);
}

// f32->bf16 convert for the three weight matrices only (12 MB).
__global__ void cvt_w(const float* __restrict__ wq, const float* __restrict__ wk,
                      const float* __restrict__ wv,
                      unsigned short* __restrict__ wqb, unsigned short* __restrict__ wkb,
                      unsigned short* __restrict__ wvb){
  long i = (long)blockIdx.x * 256 + threadIdx.x;   // 786432 f32x4 units
  const float* src; unsigned short* dst; long off;
  if (i < 262144L)      { src = wq; dst = wqb; off = i; }
  else if (i < 524288L) { src = wk; dst = wkb; off = i - 262144L; }
  else                  { src = wv; dst = wvb; off = i - 524288L; }
  f32x4 f = ((const f32x4*)src)[off];
  u16x4 o;
  o[0] = f2bf(f[0]); o[1] = f2bf(f[1]); o[2] = f2bf(f[2]); o[3] = f2bf(f[3]);
  ((u16x4*)dst)[off] = o;
}

// ---------------------------------------------------------------------------
// Unified QKV GEMM (R2 structure + fused A-conversion).
// kv-role (wg 0..1023): C[32768 x 2048] = d_f32 @ [Wk;Wv]^T + bias.
// q-role (wg 1024..1031): Q[512 x 1024] = s_f32 @ Wq^T + bq.
// 256x256 tile, BK=32, 8 waves (2Mx4N), per-wave 128x64.
// A: raw f32 (row stride 4096 B) -> per-tile reg prefetch (4 dwordx4/wave,
//    issued at tile top) -> end-of-tile cvt + 2 ds_write_b128 into swizzled
//    bf16 layout (position p holds source chunk p^((row>>1)&3) — identical
//    to the gll16 pre-swizzle, so the read path is untouched).
// B: bf16 weights via gll16, 4-slot ring staged 3 ahead (R2 verbatim).
// Boundary: lgkmcnt(0) (publish ds_writes) + counted vmcnt (B-ring) +
// s_barrier. A-loads never outstanding at the boundary (cvt drained them;
// in-order vmcnt retire also guarantees all older B stages completed).
// ---------------------------------------------------------------------------
__global__ __launch_bounds__(512, 2) void gemm_qkv(
    const float* __restrict__ dA,             // [32768][1024] f32 (t*8+b rows)
    const float* __restrict__ sA,             // [512][1024] f32
    const unsigned short* __restrict__ Wkv,   // [2048][1024] bf16 (Wk rows, then Wv)
    const unsigned short* __restrict__ Wq,    // [1024][1024] bf16
    const float* __restrict__ bq,
    const float* __restrict__ bk,
    const float* __restrict__ bv,
    unsigned short* __restrict__ Qout,
    unsigned short* __restrict__ Kout,
    unsigned short* __restrict__ Vout)
{
  __shared__ unsigned short As[4][256*32];
  __shared__ unsigned short Bs[4][256*32];

  const int nwg = gridDim.x;                 // 1032 (= 8 x 129)
  const int cpx = nwg >> 3;
  const int orig = blockIdx.x;
  const int wg = (orig & 7) * cpx + (orig >> 3);   // bijective XCD swizzle
  const int tid = threadIdx.x;
  const int lane = tid & 63, w = tid >> 6;   // 8 waves
  const int l15 = lane & 15, lg = lane >> 4;
  const int wm = w >> 2, wn = w & 3;

  const bool isQ = (wg >= 1024);
  int mt, nt;
  const float* Af; const unsigned short* Bb;
  if (!isQ){ mt = wg >> 3; nt = wg & 7; Af = dA; Bb = Wkv; }
  else     { int qi = wg - 1024; mt = qi >> 2; nt = qi & 3; Af = sA; Bb = Wq; }

  // ---- A f32 reg-staging addressing: per j, wave covers 16 rows x 128B f32.
  const int lrw = lane >> 2;                 // 0..15 (row in group)
  const int c4  = lane & 3;                  // natural 32B chunk
  const int swp = c4 ^ ((lane >> 3) & 3);    // swizzled LDS chunk position
  const char* paf[2]; unsigned wadr[2];
  #pragma unroll
  for (int j = 0; j < 2; ++j){
    int rowg = j*128 + w*16 + lrw;
    paf[j] = (const char*)Af + (size_t)(mt*256 + rowg) * 4096 + (unsigned)(c4*32);
    wadr[j] = (unsigned)(rowg*64 + (swp << 4));
  }

  // ---- B staging (R2 verbatim): pre-swizzled global source, linear dest.
  const int lr = lane >> 2;
  const int schunk = (((lane & 3) ^ ((lane >> 3) & 3)) << 4);
  const char* pb[2]; unsigned ldso[2];
  #pragma unroll
  for (int j = 0; j < 2; ++j){
    int grow = j*128 + w*16 + lr;
    pb[j] = (const char*)Bb + (size_t)(nt*256 + grow)*2048 + schunk;
    ldso[j] = (unsigned)(j*8192 + w*1024);   // wave-uniform; HW adds lane*16
  }

  #define STAGE_B(t) { char* dst = (char*)&Bs[(t)&3][0]; \
    gll16(pb[0] + (size_t)(t)*64, dst + ldso[0]); \
    gll16(pb[1] + (size_t)(t)*64, dst + ldso[1]); }

  // A prefetch registers (single set; loads live for ~1 tile body)
  f32x4 la0, la1, la2, la3;
  #define LOAD_A(tn) { \
    la0 = *(const f32x4*)(paf[0] + (size_t)(tn)*128); \
    la1 = *(const f32x4*)(paf[0] + (size_t)(tn)*128 + 16); \
    la2 = *(const f32x4*)(paf[1] + (size_t)(tn)*128); \
    la3 = *(const f32x4*)(paf[1] + (size_t)(tn)*128 + 16); }

  #define CVT_WRITE_A(buf_) { \
    char* dstA = (char*)&As[buf_][0]; \
    bf16x8 t0, t1; \
    t0[0]=(__bf16)la0[0]; t0[1]=(__bf16)la0[1]; t0[2]=(__bf16)la0[2]; t0[3]=(__bf16)la0[3]; \
    t0[4]=(__bf16)la1[0]; t0[5]=(__bf16)la1[1]; t0[6]=(__bf16)la1[2]; t0[7]=(__bf16)la1[3]; \
    t1[0]=(__bf16)la2[0]; t1[1]=(__bf16)la2[1]; t1[2]=(__bf16)la2[2]; t1[3]=(__bf16)la2[3]; \
    t1[4]=(__bf16)la3[0]; t1[5]=(__bf16)la3[1]; t1[6]=(__bf16)la3[2]; t1[7]=(__bf16)la3[3]; \
    *(bf16x8*)(dstA + wadr[0]) = t0; \
    *(bf16x8*)(dstA + wadr[1]) = t1; }

  // ---- fragment read offsets (swizzle: chunk = lg ^ ((row>>1)&3)) ----
  const unsigned cswz = ((unsigned)(lg ^ ((l15 >> 1) & 3))) << 4;
  const unsigned aoff = (unsigned)(wm*128 + l15)*64 + cswz;   // + mf*1024
  const unsigned boff = (unsigned)(wn*64  + l15)*64 + cswz;   // + nf*1024

  const f32x4 fz = {0.f, 0.f, 0.f, 0.f};
  f32x4 acc[8][4];
  #pragma unroll
  for (int m = 0; m < 8; ++m)
    #pragma unroll
    for (int n = 0; n < 4; ++n) acc[m][n] = fz;

  // ---- prologue: B tiles 0,1,2 (gll16); A(0) via regs; publish; barrier.
  STAGE_B(0) STAGE_B(1) STAGE_B(2)
  LOAD_A(0)
  CVT_WRITE_A(0)                              // drains A(0) + all older B
  asm volatile("s_waitcnt lgkmcnt(0)" ::: "memory");
  __builtin_amdgcn_sched_barrier(0);
  __builtin_amdgcn_s_barrier();
  __builtin_amdgcn_sched_barrier(0);

  #pragma unroll 1
  for (int t = 0; t < KTILES; ++t){
    const char* as = (const char*)&As[t & 3][0];
    const char* bs = (const char*)&Bs[t & 3][0];

    // ---- tile top: issue next A f32 loads (prefetch; no consumer yet)
    if (t + 1 < KTILES) { LOAD_A(t + 1) }
    __builtin_amdgcn_sched_barrier(0);

    // ---- half 1: frag reads + stage-B(t+3), 16 MFMA
    bf16x8 af0[4], bfr[4];
    #pragma unroll
    for (int mf = 0; mf < 4; ++mf) af0[mf] = *(const bf16x8*)(as + aoff + mf*1024u);
    #pragma unroll
    for (int nf = 0; nf < 4; ++nf) bfr[nf] = *(const bf16x8*)(bs + boff + nf*1024u);
    if (t + 3 < KTILES) STAGE_B(t + 3)
    __builtin_amdgcn_s_setprio(1);
    #pragma unroll
    for (int mf = 0; mf < 4; ++mf)
      #pragma unroll
      for (int nf = 0; nf < 4; ++nf)
        acc[mf][nf] = __builtin_amdgcn_mfma_f32_16x16x32_bf16(af0[mf], bfr[nf], acc[mf][nf], 0, 0, 0);
    __builtin_amdgcn_s_setprio(0);

    // ---- half 2: frag reads, 16 MFMA
    bf16x8 af1[4];
    #pragma unroll
    for (int mf = 0; mf < 4; ++mf) af1[mf] = *(const bf16x8*)(as + aoff + (4 + mf)*1024u);
    __builtin_amdgcn_s_setprio(1);
    #pragma unroll
    for (int mf = 0; mf < 4; ++mf)
      #pragma unroll
      for (int nf = 0; nf < 4; ++nf)
        acc[4 + mf][nf] = __builtin_amdgcn_mfma_f32_16x16x32_bf16(af1[mf], bfr[nf], acc[4 + mf][nf], 0, 0, 0);
    __builtin_amdgcn_s_setprio(0);

    // ---- tile end: cvt + ds_write A(t+1) (loads long since landed)
    __builtin_amdgcn_sched_barrier(0);
    if (t + 1 < KTILES) { CVT_WRITE_A((t + 1) & 3) }
    __builtin_amdgcn_sched_barrier(0);
    asm volatile("s_waitcnt lgkmcnt(0)" ::: "memory");   // publish ds_writes
    __builtin_amdgcn_sched_barrier(0);
    // B-ring counted wait (A never outstanding here; in-order retire
    // already forced B(t+1) complete via the cvt's vmcnt wait)
    if (t < KTILES - 3)       { asm volatile("s_waitcnt vmcnt(4)" ::: "memory"); }
    else if (t == KTILES - 3) { asm volatile("s_waitcnt vmcnt(2)" ::: "memory"); }
    else if (t == KTILES - 2) { asm volatile("s_waitcnt vmcnt(0)" ::: "memory"); }
    __builtin_amdgcn_s_barrier();
    __builtin_amdgcn_sched_barrier(0);
  }

  // ---- epilogue: bias + bf16 store
  int ccol; unsigned short* Cb; const float* bias;
  if (isQ)         { Cb = Qout; bias = bq; ccol = nt*256 + wn*64; }
  else if (nt < 4) { Cb = Kout; bias = bk; ccol = (nt & 3)*256 + wn*64; }
  else             { Cb = Vout; bias = bv; ccol = (nt & 3)*256 + wn*64; }
  float bvv[4];
  #pragma unroll
  for (int nf = 0; nf < 4; ++nf) bvv[nf] = bias[ccol + nf*16 + l15];
  #pragma unroll
  for (int mf = 0; mf < 8; ++mf){
    #pragma unroll
    for (int r = 0; r < 4; ++r){
      size_t row = (size_t)(mt*256 + wm*128 + mf*16 + lg*4 + r);
      unsigned short* cp = Cb + row*1024 + ccol;
      #pragma unroll
      for (int nf = 0; nf < 4; ++nf)
        cp[nf*16 + l15] = f2bf(acc[mf][nf][r] + bvv[nf]);
    }
  }
  #undef STAGE_B
  #undef LOAD_A
  #undef CVT_WRITE_A
}

// one block per (b*16+h, chunk). 256 threads = 4 waves; wave w owns slots [16w,16w+16).
__global__ __launch_bounds__(256) void attn_kernel(
    const unsigned short* __restrict__ Q,
    const unsigned short* __restrict__ K,
    const unsigned short* __restrict__ V,
    float* __restrict__ P)
{
  __shared__ unsigned short Qs[64*64];
  __shared__ unsigned short Ks[64*64];
  __shared__ unsigned short Vt[80*64];
  __shared__ unsigned short Al[64*64];
  __shared__ float red[256];

  const int bh = blockIdx.x;
  const int chunk = blockIdx.y;
  const int bb = bh >> 4, h = bh & 15;
  const int tid = threadIdx.x;
  const int lane = tid & 63, w = tid >> 6;
  const int l15 = lane & 15, lg = lane >> 4;
  const int lrow = lane >> 3, lch = (lane & 7) << 4;

  for (int i = tid; i < 16*64; i += 256){
    int r = i >> 6;
    Vt[(64 + r)*64 + (i & 63)] = (r == 0) ? (unsigned short)0x3F80 : (unsigned short)0;
  }

  #pragma unroll
  for (int j = 0; j < 2; ++j){
    int row = w*16 + j*8 + lrow;
    int sw = lch ^ ((row & 7) << 4);
    const char* g = (const char*)Q + (size_t)(row*BATCH + bb)*2048 + h*128 + sw;
    gll16(g, (char*)Qs + (w*16 + j*8)*128);
  }

  const f32x4 fz = {0.f, 0.f, 0.f, 0.f};
  f32x4 acc[5];
  #pragma unroll
  for (int nb = 0; nb < 5; ++nb) acc[nb] = fz;

  const int vtok = tid >> 2;
  const int vcg  = tid & 3;
  const int t0 = chunk * CHTOK;

  for (int tt = 0; tt < CHTOK/64; ++tt){
    const int tb = t0 + tt*64;
    #pragma unroll
    for (int j = 0; j < 2; ++j){
      int row = w*16 + j*8 + lrow;
      int sw = lch ^ ((row & 7) << 4);
      const char* g = (const char*)K + (size_t)((size_t)(tb + row)*BATCH + bb)*2048 + h*128 + sw;
      gll16(g, (char*)Ks + (w*16 + j*8)*128);
    }
    const char* vg = (const char*)V + (size_t)((size_t)(tb + vtok)*BATCH + bb)*2048 + h*128 + vcg*32;
    u16x8 v0 = *(const u16x8*)vg;
    u16x8 v1 = *(const u16x8*)(vg + 16);
    __syncthreads();

    bf16x8 qa[2];
    #pragma unroll
    for (int kk = 0; kk < 2; ++kk){
      int row = w*16 + l15;
      qa[kk] = *(const bf16x8*)((const char*)Qs + row*128 + ((lg*16 + kk*64) ^ ((row & 7) << 4)));
    }
    float e[4][4];
    #pragma unroll
    for (int nb = 0; nb < 4; ++nb){
      f32x4 s = fz;
      #pragma unroll
      for (int kk = 0; kk < 2; ++kk){
        int row = nb*16 + l15;
        bf16x8 kb = *(const bf16x8*)((const char*)Ks + row*128 + ((lg*16 + kk*64) ^ ((row & 7) << 4)));
        s = __builtin_amdgcn_mfma_f32_16x16x32_bf16(qa[kk], kb, s, 0, 0, 0);
      }
      #pragma unroll
      for (int r = 0; r < 4; ++r) e[nb][r] = __expf(s[r] * 0.125f);
    }
    #pragma unroll
    for (int nb = 0; nb < 4; ++nb){
      float cp = e[nb][0] + e[nb][1] + e[nb][2] + e[nb][3];
      cp += __shfl_xor(cp, 16);
      cp += __shfl_xor(cp, 32);
      if (lg == 0) red[w*64 + nb*16 + l15] = cp;
    }
    __syncthreads();

    #pragma unroll
    for (int nb = 0; nb < 4; ++nb){
      int col = nb*16 + l15;
      float dn = red[col] + red[64 + col] + red[128 + col] + red[192 + col];
      float inv = 1.0f / dn;
      #pragma unroll
      for (int r = 0; r < 4; ++r){
        int row = w*16 + lg*4 + r;
        Al[row*64 + ((((2*col)) ^ ((row & 7) << 4)) >> 1)] = f2bf(e[nb][r] * inv);
      }
    }
    #pragma unroll
    for (int ee = 0; ee < 8; ++ee){
      int c0 = vcg*16 + ee;
      int sw0 = (((c0 & 7) ^ (c0 >> 3)) & 7) << 4;
      Vt[c0*64 + (((2*vtok) ^ sw0) >> 1)] = v0[ee];
    }
    #pragma unroll
    for (int ee = 0; ee < 8; ++ee){
      int c1 = vcg*16 + 8 + ee;
      int sw1 = (((c1 & 7) ^ (c1 >> 3)) & 7) << 4;
      Vt[c1*64 + (((2*vtok) ^ sw1) >> 1)] = v1[ee];
    }
    __syncthreads();

    bf16x8 aa[2];
    #pragma unroll
    for (int kk = 0; kk < 2; ++kk){
      int row = w*16 + l15;
      aa[kk] = *(const bf16x8*)((const char*)Al + row*128 + ((lg*16 + kk*64) ^ ((row & 7) << 4)));
    }
    #pragma unroll
    for (int nb = 0; nb < 5; ++nb){
      #pragma unroll
      for (int kk = 0; kk < 2; ++kk){
        int row = nb*16 + l15;
        int sw = (((row & 7) ^ (row >> 3)) & 7) << 4;
        bf16x8 vb = *(const bf16x8*)((const char*)Vt + row*128 + ((lg*16 + kk*64) ^ sw));
        acc[nb] = __builtin_amdgcn_mfma_f32_16x16x32_bf16(aa[kk], vb, acc[nb], 0, 0, 0);
      }
    }
  }

  float* Pb = P + (size_t)(bh*NCHUNK + chunk) * 64 * 80;
  #pragma unroll
  for (int nb = 0; nb < 5; ++nb){
    #pragma unroll
    for (int r = 0; r < 4; ++r){
      int s = w*16 + lg*4 + r;
      Pb[(size_t)s*80 + nb*16 + l15] = acc[nb][r];
    }
  }
}

__global__ void reduce_out(const float* __restrict__ P, float* __restrict__ out){
  int flat = blockIdx.x * 256 + threadIdx.x;
  int c = flat & 63, s = (flat >> 6) & 63, bh = flat >> 12;
  int bb = bh >> 4, h = bh & 15;
  float sc = 0.f, sn = 0.f;
  #pragma unroll
  for (int ch = 0; ch < NCHUNK; ++ch){
    const float* base = P + ((size_t)(bh*NCHUNK + ch)*64 + s)*80;
    sc += base[c];
    sn += base[64];
  }
  out[((size_t)s*BATCH + bb)*1024 + h*64 + c] = sc / (sn + 0.001f);
}

extern "C" void kernel_launch(void* const* d_in, const int* in_sizes, int n_in,
                              void* d_out, int out_size, void* d_ws, size_t ws_size,
                              hipStream_t stream)
{
  const float* s  = (const float*)d_in[0];
  const float* d  = (const float*)d_in[1];
  const float* Wq = (const float*)d_in[2];
  const float* bq = (const float*)d_in[3];
  const float* Wk = (const float*)d_in[4];
  const float* bk = (const float*)d_in[5];
  const float* Wv = (const float*)d_in[6];
  const float* bv = (const float*)d_in[7];
  float* out = (float*)d_out;

  char* ws = (char*)d_ws;
  unsigned short* wqb = (unsigned short*)(ws + 68157440);    //  2,097,152
  unsigned short* wkb = (unsigned short*)(ws + 70254592);    //  2,097,152 (Wk rows 0..1023)
  unsigned short* wvb = (unsigned short*)(ws + 72351744);    //  2,097,152 (Wv = wkb rows 1024..2047)
  unsigned short* Qw  = (unsigned short*)(ws + 74448896);    //  1,048,576
  unsigned short* Kw  = (unsigned short*)(ws + 75497472);    // 67,108,864
  unsigned short* Vw  = (unsigned short*)(ws + 142606336);   // 67,108,864
  float*          Pw  = (float*)(ws + 209715200);            // 20,971,520

  (void)in_sizes; (void)n_in; (void)out_size; (void)ws_size;

  cvt_w<<<3072, 256, 0, stream>>>(Wq, Wk, Wv, wqb, wkb, wvb);

  gemm_qkv<<<1032, 512, 0, stream>>>(d, s, wkb, wqb, bq, bk, bv, Qw, Kw, Vw);

  attn_kernel<<<dim3(128, NCHUNK), 256, 0, stream>>>(Qw, Kw, Vw, Pw);

  reduce_out<<<(TS*BATCH*HC)/256, 256, 0, stream>>>(Pw, out);
}

// Round 13
// 260.888 us; speedup vs baseline: 1.1684x; 1.1684x over previous
//
#include <hip/hip_runtime.h>

// SlotAttention on MI355X (gfx950).
// R12: R10 config (best: 243.8us) with BK=64 in the GEMM — halves the
// per-K-tile boundary count (32 -> 16). Diagnosis: ~1600 cyc of per-boundary
// stall (m233's structural stage+vmcnt+barrier overhead) dominates the tile
// budget; boundary count, not bytes, is the lever. Same 128 KiB LDS and
// occupancy (2-slot ring of 32KB+32KB), depth-1 staging, one __syncthreads
// per K-64 tile. 128B LDS rows use a 3-bit XOR swizzle (2 lanes/bank = free).
// cvt_all / attn / reduce unchanged from R10.

#define TS 64
#define TD 4096
#define BATCH 8
#define HC 1024
#define NHEAD 16
#define MD (TD*BATCH)   // 32768
#define MS (TS*BATCH)   // 512
#define NCHUNK 8
#define CHTOK (TD/NCHUNK) // 512

#define KT64 16         // K=1024 / BK=64

typedef __attribute__((ext_vector_type(8))) __bf16 bf16x8;
typedef __attribute__((ext_vector_type(4))) float f32x4;
typedef __attribute__((ext_vector_type(4))) unsigned short u16x4;
typedef __attribute__((ext_vector_type(8))) unsigned short u16x8;

__device__ __forceinline__ unsigned short f2bf(float x){
  union { float f; unsigned u; } v; v.f = x;
  unsigned r = v.u + 0x7FFFu + ((v.u >> 16) & 1u);
  return (unsigned short)(r >> 16);
}

__device__ __forceinline__ void gll16(const void* g, void* l){
  __builtin_amdgcn_global_load_lds((__attribute__((address_space(1))) void*)g,
                                   (__attribute__((address_space(3))) void*)l, 16, 0, 0);
}

// Fused f32->bf16 convert for all five inputs (one launch).
__global__ void cvt_all(const float* __restrict__ d, const float* __restrict__ s,
                        const float* __restrict__ wq, const float* __restrict__ wk,
                        const float* __restrict__ wv,
                        unsigned short* __restrict__ dbf, unsigned short* __restrict__ sbf,
                        unsigned short* __restrict__ wqb, unsigned short* __restrict__ wkb,
                        unsigned short* __restrict__ wvb){
  long i = (long)blockIdx.x * 256 + threadIdx.x;
  const float* src; unsigned short* dst; long off;
  if (i < 8388608L)      { src = d;  dst = dbf; off = i; }
  else if (i < 8519680L) { src = s;  dst = sbf; off = i - 8388608L; }
  else if (i < 8781824L) { src = wq; dst = wqb; off = i - 8519680L; }
  else if (i < 9043968L) { src = wk; dst = wkb; off = i - 8781824L; }
  else                   { src = wv; dst = wvb; off = i - 9043968L; }
  f32x4 f = ((const f32x4*)src)[off];
  u16x4 o;
  o[0] = f2bf(f[0]); o[1] = f2bf(f[1]); o[2] = f2bf(f[2]); o[3] = f2bf(f[3]);
  ((u16x4*)dst)[off] = o;
}

// ---------------------------------------------------------------------------
// Unified QKV GEMM, BK=64 / 16-boundary version.
// kv-role (wg 0..1023): C[32768 x 2048] = dbf @ [Wk;Wv]^T + bias.
// q-role (wg 1024..1031): Q[512 x 1024] = sbf @ Wq^T + bq.
// 256x256 tile, 8 waves (2Mx4N), per-wave 128x64. BK=64.
// LDS: 2 slots x (A 32KB + B 32KB) = 128 KiB; tile t -> slot t&1.
// Per tile: stage(t+1) -> opposite slot (8 gll16/wave, issued first), then
// 2 k-halves x {12 ds_read_b128 + 32 MFMA}, then ONE __syncthreads
// (vmcnt0+lgkm0+barrier). Stage was issued a full tile (~5000 cyc) before
// its drain -> HBM latency fully covered. WAR: slot (t+1)&1's reads were
// consumed before the previous boundary barrier.
// LDS rows = 128B (8 x 16B chunks); position p = chunk ^ S(row),
// S(row) = ((row>>1)&3) | ((row&1)<<2). 16-lane read groups hit 8 distinct
// positions, 2 lanes/bank -> conflict-free (m136). Staging pre-swizzles the
// global source with the same S; gll16 dest stays linear.
// ---------------------------------------------------------------------------
__global__ __launch_bounds__(512, 2) void gemm_qkv(
    const unsigned short* __restrict__ A,     // dbf [32768][1024]
    const unsigned short* __restrict__ Sb,    // sbf [512][1024]
    const unsigned short* __restrict__ Wkv,   // [2048][1024] (Wk rows, then Wv)
    const unsigned short* __restrict__ Wq,    // [1024][1024]
    const float* __restrict__ bq,
    const float* __restrict__ bk,
    const float* __restrict__ bv,
    unsigned short* __restrict__ Qout,
    unsigned short* __restrict__ Kout,
    unsigned short* __restrict__ Vout)
{
  __shared__ unsigned short As[2][256*64];   // 32 KB per slot
  __shared__ unsigned short Bs[2][256*64];   // 32 KB per slot

  const int nwg = gridDim.x;                 // 1032 (= 8 x 129)
  const int cpx = nwg >> 3;
  const int orig = blockIdx.x;
  const int wg = (orig & 7) * cpx + (orig >> 3);   // bijective XCD swizzle
  const int tid = threadIdx.x;
  const int lane = tid & 63, w = tid >> 6;   // 8 waves
  const int l15 = lane & 15, lg = lane >> 4;
  const int wm = w >> 2, wn = w & 3;

  const bool isQ = (wg >= 1024);
  int mt, nt;
  const unsigned short* Ab; const unsigned short* Bb;
  if (!isQ){ mt = wg >> 3; nt = wg & 7; Ab = A;  Bb = Wkv; }
  else     { int qi = wg - 1024; mt = qi >> 2; nt = qi & 3; Ab = Sb; Bb = Wq; }

  // ---- staging: each gll16 covers 8 rows x 128B; 4 per matrix per wave.
  const int ri = lane >> 3;                  // row in 8-row granule
  const int Sst = ((ri >> 1) & 3) | ((ri & 1) << 2);
  const unsigned schunk = (unsigned)(((lane & 7) ^ Sst) << 4);  // pre-swizzled src
  const char* pa[4]; const char* pb[4]; unsigned ldso[4];
  #pragma unroll
  for (int j = 0; j < 4; ++j){
    int grow = w*32 + j*8 + ri;
    pa[j] = (const char*)Ab + (size_t)(mt*256 + grow)*2048 + schunk;
    pb[j] = (const char*)Bb + (size_t)(nt*256 + grow)*2048 + schunk;
    ldso[j] = (unsigned)((w*32 + j*8) * 128);   // wave-uniform; HW adds lane*16
  }

  #define STAGE_AB(t_, sl_) { \
    const size_t ko = (size_t)(t_) * 128; \
    char* da = (char*)&As[sl_][0]; char* db = (char*)&Bs[sl_][0]; \
    gll16(pa[0] + ko, da + ldso[0]); \
    gll16(pa[1] + ko, da + ldso[1]); \
    gll16(pa[2] + ko, da + ldso[2]); \
    gll16(pa[3] + ko, da + ldso[3]); \
    gll16(pb[0] + ko, db + ldso[0]); \
    gll16(pb[1] + ko, db + ldso[1]); \
    gll16(pb[2] + ko, db + ldso[2]); \
    gll16(pb[3] + ko, db + ldso[3]); \
    __builtin_amdgcn_sched_barrier(0); }

  // ---- fragment read offsets: row*128 + ((h*4+lg)^S(l15))<<4, + frag*2048
  const int Sr = ((l15 >> 1) & 3) | ((l15 & 1) << 2);
  const unsigned ck0 = (unsigned)(((0 + lg) ^ Sr) << 4);
  const unsigned ck1 = (unsigned)(((4 + lg) ^ Sr) << 4);
  const unsigned arow = (unsigned)(wm*128 + l15) * 128;   // + mf*2048
  const unsigned brow = (unsigned)(wn*64  + l15) * 128;   // + nf*2048

  const f32x4 fz = {0.f, 0.f, 0.f, 0.f};
  f32x4 acc[8][4];
  #pragma unroll
  for (int m = 0; m < 8; ++m)
    #pragma unroll
    for (int n = 0; n < 4; ++n) acc[m][n] = fz;

  // One k-half (32 of the 64 k): 12 ds_read_b128 + 32 MFMA, split 2x16.
  #define HALF(as_, bs_, ckh_) { \
    bf16x8 af0[4], bfr[4]; \
    _Pragma("unroll") \
    for (int mf = 0; mf < 4; ++mf) af0[mf] = *(const bf16x8*)(as_ + arow + mf*2048u + (ckh_)); \
    _Pragma("unroll") \
    for (int nf = 0; nf < 4; ++nf) bfr[nf] = *(const bf16x8*)(bs_ + brow + nf*2048u + (ckh_)); \
    __builtin_amdgcn_s_setprio(1); \
    _Pragma("unroll") \
    for (int mf = 0; mf < 4; ++mf) \
      _Pragma("unroll") \
      for (int nf = 0; nf < 4; ++nf) \
        acc[mf][nf] = __builtin_amdgcn_mfma_f32_16x16x32_bf16(af0[mf], bfr[nf], acc[mf][nf], 0, 0, 0); \
    __builtin_amdgcn_s_setprio(0); \
    bf16x8 af1[4]; \
    _Pragma("unroll") \
    for (int mf = 0; mf < 4; ++mf) af1[mf] = *(const bf16x8*)(as_ + arow + (4 + mf)*2048u + (ckh_)); \
    __builtin_amdgcn_s_setprio(1); \
    _Pragma("unroll") \
    for (int mf = 0; mf < 4; ++mf) \
      _Pragma("unroll") \
      for (int nf = 0; nf < 4; ++nf) \
        acc[4 + mf][nf] = __builtin_amdgcn_mfma_f32_16x16x32_bf16(af1[mf], bfr[nf], acc[4 + mf][nf], 0, 0, 0); \
    __builtin_amdgcn_s_setprio(0); }

  // ---- prologue
  STAGE_AB(0, 0)
  __syncthreads();

  // ---- main loop: 16 K-64 tiles, ONE boundary each
  #pragma unroll 1
  for (int t = 0; t < KT64; ++t){
    if (t + 1 < KT64) STAGE_AB(t + 1, (t + 1) & 1)
    const char* as = (const char*)&As[t & 1][0];
    const char* bs = (const char*)&Bs[t & 1][0];
    HALF(as, bs, ck0)
    HALF(as, bs, ck1)
    __syncthreads();
  }

  // ---- epilogue: bias + bf16 store
  int ccol; unsigned short* Cb; const float* bias;
  if (isQ)         { Cb = Qout; bias = bq; ccol = nt*256 + wn*64; }
  else if (nt < 4) { Cb = Kout; bias = bk; ccol = (nt & 3)*256 + wn*64; }
  else             { Cb = Vout; bias = bv; ccol = (nt & 3)*256 + wn*64; }
  float bvv[4];
  #pragma unroll
  for (int nf = 0; nf < 4; ++nf) bvv[nf] = bias[ccol + nf*16 + l15];
  #pragma unroll
  for (int mf = 0; mf < 8; ++mf){
    #pragma unroll
    for (int r = 0; r < 4; ++r){
      size_t row = (size_t)(mt*256 + wm*128 + mf*16 + lg*4 + r);
      unsigned short* cp = Cb + row*1024 + ccol;
      #pragma unroll
      for (int nf = 0; nf < 4; ++nf)
        cp[nf*16 + l15] = f2bf(acc[mf][nf][r] + bvv[nf]);
    }
  }
  #undef STAGE_AB
  #undef HALF
}

// one block per (b*16+h, chunk). 256 threads = 4 waves; wave w owns slots [16w,16w+16).
__global__ __launch_bounds__(256) void attn_kernel(
    const unsigned short* __restrict__ Q,
    const unsigned short* __restrict__ K,
    const unsigned short* __restrict__ V,
    float* __restrict__ P)
{
  __shared__ unsigned short Qs[64*64];
  __shared__ unsigned short Ks[64*64];
  __shared__ unsigned short Vt[80*64];
  __shared__ unsigned short Al[64*64];
  __shared__ float red[256];

  const int bh = blockIdx.x;
  const int chunk = blockIdx.y;
  const int bb = bh >> 4, h = bh & 15;
  const int tid = threadIdx.x;
  const int lane = tid & 63, w = tid >> 6;
  const int l15 = lane & 15, lg = lane >> 4;
  const int lrow = lane >> 3, lch = (lane & 7) << 4;

  for (int i = tid; i < 16*64; i += 256){
    int r = i >> 6;
    Vt[(64 + r)*64 + (i & 63)] = (r == 0) ? (unsigned short)0x3F80 : (unsigned short)0;
  }

  #pragma unroll
  for (int j = 0; j < 2; ++j){
    int row = w*16 + j*8 + lrow;
    int sw = lch ^ ((row & 7) << 4);
    const char* g = (const char*)Q + (size_t)(row*BATCH + bb)*2048 + h*128 + sw;
    gll16(g, (char*)Qs + (w*16 + j*8)*128);
  }

  const f32x4 fz = {0.f, 0.f, 0.f, 0.f};
  f32x4 acc[5];
  #pragma unroll
  for (int nb = 0; nb < 5; ++nb) acc[nb] = fz;

  const int vtok = tid >> 2;
  const int vcg  = tid & 3;
  const int t0 = chunk * CHTOK;

  for (int tt = 0; tt < CHTOK/64; ++tt){
    const int tb = t0 + tt*64;
    #pragma unroll
    for (int j = 0; j < 2; ++j){
      int row = w*16 + j*8 + lrow;
      int sw = lch ^ ((row & 7) << 4);
      const char* g = (const char*)K + (size_t)((size_t)(tb + row)*BATCH + bb)*2048 + h*128 + sw;
      gll16(g, (char*)Ks + (w*16 + j*8)*128);
    }
    const char* vg = (const char*)V + (size_t)((size_t)(tb + vtok)*BATCH + bb)*2048 + h*128 + vcg*32;
    u16x8 v0 = *(const u16x8*)vg;
    u16x8 v1 = *(const u16x8*)(vg + 16);
    __syncthreads();

    bf16x8 qa[2];
    #pragma unroll
    for (int kk = 0; kk < 2; ++kk){
      int row = w*16 + l15;
      qa[kk] = *(const bf16x8*)((const char*)Qs + row*128 + ((lg*16 + kk*64) ^ ((row & 7) << 4)));
    }
    float e[4][4];
    #pragma unroll
    for (int nb = 0; nb < 4; ++nb){
      f32x4 s = fz;
      #pragma unroll
      for (int kk = 0; kk < 2; ++kk){
        int row = nb*16 + l15;
        bf16x8 kb = *(const bf16x8*)((const char*)Ks + row*128 + ((lg*16 + kk*64) ^ ((row & 7) << 4)));
        s = __builtin_amdgcn_mfma_f32_16x16x32_bf16(qa[kk], kb, s, 0, 0, 0);
      }
      #pragma unroll
      for (int r = 0; r < 4; ++r) e[nb][r] = __expf(s[r] * 0.125f);
    }
    #pragma unroll
    for (int nb = 0; nb < 4; ++nb){
      float cp = e[nb][0] + e[nb][1] + e[nb][2] + e[nb][3];
      cp += __shfl_xor(cp, 16);
      cp += __shfl_xor(cp, 32);
      if (lg == 0) red[w*64 + nb*16 + l15] = cp;
    }
    __syncthreads();

    #pragma unroll
    for (int nb = 0; nb < 4; ++nb){
      int col = nb*16 + l15;
      float dn = red[col] + red[64 + col] + red[128 + col] + red[192 + col];
      float inv = 1.0f / dn;
      #pragma unroll
      for (int r = 0; r < 4; ++r){
        int row = w*16 + lg*4 + r;
        Al[row*64 + ((((2*col)) ^ ((row & 7) << 4)) >> 1)] = f2bf(e[nb][r] * inv);
      }
    }
    #pragma unroll
    for (int ee = 0; ee < 8; ++ee){
      int c0 = vcg*16 + ee;
      int sw0 = (((c0 & 7) ^ (c0 >> 3)) & 7) << 4;
      Vt[c0*64 + (((2*vtok) ^ sw0) >> 1)] = v0[ee];
    }
    #pragma unroll
    for (int ee = 0; ee < 8; ++ee){
      int c1 = vcg*16 + 8 + ee;
      int sw1 = (((c1 & 7) ^ (c1 >> 3)) & 7) << 4;
      Vt[c1*64 + (((2*vtok) ^ sw1) >> 1)] = v1[ee];
    }
    __syncthreads();

    bf16x8 aa[2];
    #pragma unroll
    for (int kk = 0; kk < 2; ++kk){
      int row = w*16 + l15;
      aa[kk] = *(const bf16x8*)((const char*)Al + row*128 + ((lg*16 + kk*64) ^ ((row & 7) << 4)));
    }
    #pragma unroll
    for (int nb = 0; nb < 5; ++nb){
      #pragma unroll
      for (int kk = 0; kk < 2; ++kk){
        int row = nb*16 + l15;
        int sw = (((row & 7) ^ (row >> 3)) & 7) << 4;
        bf16x8 vb = *(const bf16x8*)((const char*)Vt + row*128 + ((lg*16 + kk*64) ^ sw));
        acc[nb] = __builtin_amdgcn_mfma_f32_16x16x32_bf16(aa[kk], vb, acc[nb], 0, 0, 0);
      }
    }
  }

  float* Pb = P + (size_t)(bh*NCHUNK + chunk) * 64 * 80;
  #pragma unroll
  for (int nb = 0; nb < 5; ++nb){
    #pragma unroll
    for (int r = 0; r < 4; ++r){
      int s = w*16 + lg*4 + r;
      Pb[(size_t)s*80 + nb*16 + l15] = acc[nb][r];
    }
  }
}

__global__ void reduce_out(const float* __restrict__ P, float* __restrict__ out){
  int flat = blockIdx.x * 256 + threadIdx.x;
  int c = flat & 63, s = (flat >> 6) & 63, bh = flat >> 12;
  int bb = bh >> 4, h = bh & 15;
  float sc = 0.f, sn = 0.f;
  #pragma unroll
  for (int ch = 0; ch < NCHUNK; ++ch){
    const float* base = P + ((size_t)(bh*NCHUNK + ch)*64 + s)*80;
    sc += base[c];
    sn += base[64];
  }
  out[((size_t)s*BATCH + bb)*1024 + h*64 + c] = sc / (sn + 0.001f);
}

extern "C" void kernel_launch(void* const* d_in, const int* in_sizes, int n_in,
                              void* d_out, int out_size, void* d_ws, size_t ws_size,
                              hipStream_t stream)
{
  const float* s  = (const float*)d_in[0];
  const float* d  = (const float*)d_in[1];
  const float* Wq = (const float*)d_in[2];
  const float* bq = (const float*)d_in[3];
  const float* Wk = (const float*)d_in[4];
  const float* bk = (const float*)d_in[5];
  const float* Wv = (const float*)d_in[6];
  const float* bv = (const float*)d_in[7];
  float* out = (float*)d_out;

  char* ws = (char*)d_ws;
  unsigned short* dbf = (unsigned short*)(ws);               // 67,108,864
  unsigned short* sbf = (unsigned short*)(ws + 67108864);    //  1,048,576
  unsigned short* wqb = (unsigned short*)(ws + 68157440);    //  2,097,152
  unsigned short* wkb = (unsigned short*)(ws + 70254592);    //  2,097,152 (Wk rows 0..1023)
  unsigned short* wvb = (unsigned short*)(ws + 72351744);    //  2,097,152 (Wv = wkb rows 1024..2047)
  unsigned short* Qw  = (unsigned short*)(ws + 74448896);    //  1,048,576
  unsigned short* Kw  = (unsigned short*)(ws + 75497472);    // 67,108,864
  unsigned short* Vw  = (unsigned short*)(ws + 142606336);   // 67,108,864
  float*          Pw  = (float*)(ws + 209715200);            // 20,971,520

  (void)in_sizes; (void)n_in; (void)out_size; (void)ws_size;

  cvt_all<<<36352, 256, 0, stream>>>(d, s, Wq, Wk, Wv, dbf, sbf, wqb, wkb, wvb);

  gemm_qkv<<<1032, 512, 0, stream>>>(dbf, sbf, wkb, wqb, bq, bk, bv, Qw, Kw, Vw);

  attn_kernel<<<dim3(128, NCHUNK), 256, 0, stream>>>(Qw, Kw, Vw, Pw);

  reduce_out<<<(TS*BATCH*HC)/256, 256, 0, stream>>>(Pw, out);
}